// Round 6
// baseline (166.618 us; speedup 1.0000x reference)
//
#include <hip/hip_runtime.h>
#include <stdint.h>

// Problem constants
#define BATCH   4
#define SEQ     2048
#define DMODEL  384
#define NHEAD   6
#define NKVH    2
#define HD      64
#define MTOK    (BATCH*SEQ)   // 8192
#define NQKV    640           // 384 q + 128 k + 128 v
// 1/sqrt(HD) * log2(e): scores leave QK^T already in log2 domain -> raw v_exp_f32.
#define QSCALE  (0.125f * 1.4426950408889634f)

typedef __bf16 bf16x8 __attribute__((ext_vector_type(8)));
typedef float  f32x16 __attribute__((ext_vector_type(16)));

__device__ inline unsigned short f2bf(float f) {
  union { float f; unsigned int u; } v; v.f = f;
  return (unsigned short)((v.u + 0x7fffu + ((v.u >> 16) & 1u)) >> 16); // RNE
}
__device__ inline float bf2f(unsigned short b) {
  union { unsigned int u; float f; } v; v.u = ((unsigned int)b) << 16;
  return v.f;
}
__device__ inline unsigned int cvtpk(float lo, float hi) {
  unsigned int r;
  asm("v_cvt_pk_bf16_f32 %0, %1, %2" : "=v"(r) : "v"(lo), "v"(hi));
  return r;
}
__device__ inline float exp2_fast(float x) {   // v_exp_f32: D = 2^S0
  float r;
  asm("v_exp_f32 %0, %1" : "=v"(r) : "v"(x));
  return r;
}

#define GLOAD16(gsrc, ldst) __builtin_amdgcn_global_load_lds( \
    (const __attribute__((address_space(1))) void*)(gsrc), \
    (__attribute__((address_space(3))) void*)(ldst), 16, 0, 0)

#define WAITVN(n) asm volatile("s_waitcnt vmcnt(" #n ")" ::: "memory")

// ---------------------------------------------------------------------------
// Kernel 1: prep — X fp32->bf16 ; WT[640][384] = [Wq|Wk|Wv]^T bf16 ; WoT bf16
// ---------------------------------------------------------------------------
__global__ void prep_kernel(const float* __restrict__ X,
                            const float* __restrict__ Wq, const float* __restrict__ Wk,
                            const float* __restrict__ Wv, const float* __restrict__ Wo,
                            unsigned short* __restrict__ Xb,
                            unsigned short* __restrict__ WT,
                            unsigned short* __restrict__ WoT) {
  int idx = blockIdx.x * 256 + threadIdx.x;
  if (idx < (MTOK*DMODEL)/4) {
    float4 v = ((const float4*)X)[idx];
    union { unsigned short s[4]; uint2 u; } o;
    o.s[0] = f2bf(v.x); o.s[1] = f2bf(v.y); o.s[2] = f2bf(v.z); o.s[3] = f2bf(v.w);
    ((uint2*)Xb)[idx] = o.u;
  } else if (idx < (MTOK*DMODEL)/4 + NQKV*DMODEL) {
    int j = idx - (MTOK*DMODEL)/4;
    int n = j / DMODEL, k = j % DMODEL;
    float val = (n < 384) ? Wq[k*384 + n]
              : (n < 512) ? Wk[k*128 + (n-384)]
                          : Wv[k*128 + (n-512)];
    WT[j] = f2bf(val);
  } else if (idx < (MTOK*DMODEL)/4 + NQKV*DMODEL + DMODEL*DMODEL) {
    int j = idx - (MTOK*DMODEL)/4 - NQKV*DMODEL;
    int n = j / DMODEL, k = j % DMODEL;
    WoT[j] = f2bf(Wo[k*384 + n]);
  }
}

// ---------------------------------------------------------------------------
// Kernel 2/5: bf16 MFMA GEMM  C[M][NCOLS] = A[M][384] * BT[NCOLS][384]^T
// tile 128x64, BK=64, 4 waves (2x2), 32x32x16 MFMA. RoPE fused in epilogue.
// ---------------------------------------------------------------------------
template<int NCOLS, bool OUT_BF16, bool ROPE>
__global__ __launch_bounds__(256, 2)
void gemm_kernel(const unsigned short* __restrict__ A,
                 const unsigned short* __restrict__ BT,
                 void* __restrict__ Cout,
                 const float* __restrict__ fcos,
                 const float* __restrict__ fsin) {
  __shared__ unsigned short ldsA[128*64];
  __shared__ unsigned short ldsB[64*64];
  const int tid = threadIdx.x;
  const int wid = tid >> 6, lane = tid & 63;
  const int g = lane >> 5, l31 = lane & 31;
  const int wm = wid >> 1, wn = wid & 1;
  const int mbase = blockIdx.x * 128, nbase = blockIdx.y * 64;

  f32x16 c[2];
  #pragma unroll
  for (int i = 0; i < 2; ++i)
    #pragma unroll
    for (int r = 0; r < 16; ++r) c[i][r] = 0.f;

  for (int kt = 0; kt < DMODEL; kt += 64) {
    #pragma unroll
    for (int i = 0; i < 4; ++i) {
      int L = ((wid*4 + i) << 10) + lane*16;
      int row = L >> 7;
      int slot = (lane & 7) ^ (row & 7);
      GLOAD16(A + (mbase + row)*DMODEL + kt + slot*8, ((char*)ldsA) + L);
    }
    #pragma unroll
    for (int i = 0; i < 2; ++i) {
      int L = ((wid*2 + i) << 10) + lane*16;
      int row = L >> 7;
      int slot = (lane & 7) ^ (row & 7);
      GLOAD16(BT + (nbase + row)*DMODEL + kt + slot*8, ((char*)ldsB) + L);
    }
    __syncthreads();

    bf16x8 bf[4];
    {
      int row = wn*32 + l31;
      #pragma unroll
      for (int s = 0; s < 4; ++s) {
        int slot = ((s<<1) | g) ^ (row & 7);
        bf[s] = *(const bf16x8*)(((const char*)ldsB) + row*128 + slot*16);
      }
    }
    #pragma unroll
    for (int mt = 0; mt < 2; ++mt) {
      int row = wm*64 + mt*32 + l31;
      #pragma unroll
      for (int s = 0; s < 4; ++s) {
        int slot = ((s<<1) | g) ^ (row & 7);
        bf16x8 af = *(const bf16x8*)(((const char*)ldsA) + row*128 + slot*16);
        c[mt] = __builtin_amdgcn_mfma_f32_32x32x16_bf16(af, bf[s], c[mt], 0, 0, 0);
      }
    }
    __syncthreads();
  }

  const int n = nbase + wn*32 + l31;
  const bool isqk = ROPE && (nbase < 512);
  const float rscale = (nbase < 384) ? QSCALE : 1.0f;
  const int ri = (n & 63) >> 1;
  const bool odd = (n & 1) != 0;

  #pragma unroll
  for (int mt = 0; mt < 2; ++mt)
    #pragma unroll
    for (int rr = 0; rr < 16; ++rr) {
      int m = mbase + wm*64 + mt*32 + (rr&3) + ((rr>>2)<<3) + (g<<2);
      float val = c[mt][rr];
      if (isqk) {
        float xp = __shfl_xor(val, 1);
        int s = m & (SEQ-1);
        float cs = fcos[s*32 + ri], sn = fsin[s*32 + ri];
        val = odd ? (xp*sn + val*cs) : (val*cs - xp*sn);
        val *= rscale;
      }
      if (OUT_BF16) ((unsigned short*)Cout)[m*NCOLS + n] = f2bf(val);
      else          ((float*)Cout)[m*NCOLS + n] = val;
    }
}

// ---------------------------------------------------------------------------
// Kernel 3: V -> MFMA-fragment layout
// Vf[(b*2+kvh)][tile(64)][dt(2)][sl(2)][lane(64)][8 bf16]
// content: V[s = tile*32 + sl*16 + (lane>>5)*8 + j][hd = dt*32 + (lane&31)]
// ---------------------------------------------------------------------------
__global__ void vfrag_kernel(const unsigned short* __restrict__ qkv,
                             unsigned short* __restrict__ Vf) {
  __shared__ unsigned short tile[64][72];
  int t = threadIdx.x;
  int s0 = blockIdx.x * 64;
  int kvh = blockIdx.y;
  int b = blockIdx.z;
  #pragma unroll
  for (int p = 0; p < 2; ++p) {
    int row = (t >> 3) + p*32;
    int c8 = t & 7;
    uint4 v = *(const uint4*)(qkv + (size_t)(b*SEQ + s0 + row)*NQKV + 512 + kvh*64 + c8*8);
    *(uint4*)(&tile[row][c8*8]) = v;
  }
  __syncthreads();
  unsigned short* base = Vf + (size_t)(b*2 + kvh)*131072;
  #pragma unroll
  for (int p = 0; p < 2; ++p) {
    int c = t + p*256;           // 0..511
    int tloc = c >> 8;
    int r = c & 255;
    int dt = r >> 7, sl = (r >> 6) & 1, lane = r & 63;
    int gg = lane >> 5, ll = lane & 31;
    union { unsigned short s[8]; uint4 v; } o;
    #pragma unroll
    for (int j = 0; j < 8; ++j)
      o.s[j] = tile[tloc*32 + sl*16 + gg*8 + j][dt*32 + ll];
    *(uint4*)(base + (size_t)(s0/32 + tloc)*2048 + (dt*2 + sl)*512 + lane*8) = o.v;
  }
}

// ---------------------------------------------------------------------------
// Kernel 4: flash attention — 4 waves/block, QBLK=64 (two 32-row q-subtiles),
// in-block kv-split-4 (wave w owns kv [w*512, w*512+512), 16 tiles of 32).
// grid 768 blocks = exactly 3 blocks/CU (32KB LDS), XCD-swizzled.
// Per iter: V-frag loads issued FIRST (so compiler's V-wait = vmcnt(4),
// leaving K(t+1) in flight), then stage_k(t+1), then explicit vmcnt(8) for
// K(t). sched_barrier pins the V-before-K issue order. 4-way flash combine
// through reused staging LDS at the end; single attnO write, no partials.
// ---------------------------------------------------------------------------
__device__ __forceinline__ void stage_k(const unsigned short* Kbase, int kv0,
                                        char* kbuf, int lane) {
  #pragma unroll
  for (int i = 0; i < 4; ++i) {
    int L = (i << 10) + lane*16;
    int row = L >> 7;
    int slot = (lane & 7) ^ (row & 7);
    GLOAD16(Kbase + (size_t)(kv0 + row)*NQKV + slot*8, kbuf + L);
  }
}

// QK^T + online softmax (log2 domain, defer-max) + PV for one 32-row subtile.
#define PROC_SUB(QF, MR, LR, AC0, AC1) do {                                        \
  f32x16 c1;                                                                       \
  _Pragma("unroll")                                                                \
  for (int r = 0; r < 16; ++r) c1[r] = 0.f;                                        \
  _Pragma("unroll")                                                                \
  for (int s = 0; s < 4; ++s) {                                                    \
    int slot = ((s<<1) | g) ^ (l31 & 7);                                           \
    bf16x8 kf = *(const bf16x8*)(kb + l31*128 + slot*16);                          \
    c1 = __builtin_amdgcn_mfma_f32_32x32x16_bf16(kf, QF[s], c1, 0, 0, 0);          \
  }                                                                                \
  float x0 = fmaxf(c1[0],c1[1]), x1 = fmaxf(c1[2],c1[3]);                          \
  float x2 = fmaxf(c1[4],c1[5]), x3 = fmaxf(c1[6],c1[7]);                          \
  float x4 = fmaxf(c1[8],c1[9]), x5 = fmaxf(c1[10],c1[11]);                        \
  float x6 = fmaxf(c1[12],c1[13]), x7 = fmaxf(c1[14],c1[15]);                      \
  float y0 = fmaxf(x0,x1), y1 = fmaxf(x2,x3), y2 = fmaxf(x4,x5), y3 = fmaxf(x6,x7);\
  float pmax = fmaxf(fmaxf(y0,y1), fmaxf(y2,y3));                                  \
  pmax = fmaxf(pmax, __shfl_xor(pmax, 32));                                        \
  if (!__all(pmax <= MR + 10.f)) {                                                 \
    float mnew = fmaxf(MR, pmax);                                                  \
    float alpha = exp2_fast(MR - mnew);                                            \
    _Pragma("unroll")                                                              \
    for (int r = 0; r < 16; ++r) { AC0[r] *= alpha; AC1[r] *= alpha; }             \
    LR *= alpha;                                                                   \
    MR = mnew;                                                                     \
  }                                                                                \
  float p[16];                                                                     \
  _Pragma("unroll")                                                                \
  for (int r = 0; r < 16; ++r) p[r] = exp2_fast(c1[r] - MR);                       \
  {                                                                                \
    float s0_ = (p[0]+p[1])+(p[2]+p[3]), s1_ = (p[4]+p[5])+(p[6]+p[7]);            \
    float s2_ = (p[8]+p[9])+(p[10]+p[11]), s3_ = (p[12]+p[13])+(p[14]+p[15]);      \
    LR += (s0_+s1_)+(s2_+s3_);                                                     \
  }                                                                                \
  _Pragma("unroll")                                                                \
  for (int sl = 0; sl < 2; ++sl) {                                                 \
    int rb = sl*8;                                                                 \
    unsigned int w0  = cvtpk(p[rb+0], p[rb+1]);                                    \
    unsigned int w1  = cvtpk(p[rb+2], p[rb+3]);                                    \
    unsigned int wh0 = cvtpk(p[rb+4], p[rb+5]);                                    \
    unsigned int wh1 = cvtpk(p[rb+6], p[rb+7]);                                    \
    unsigned int t0 = g ? w0 : wh0;                                                \
    unsigned int t1 = g ? w1 : wh1;                                                \
    unsigned int r0 = __shfl_xor(t0, 32);                                          \
    unsigned int r1 = __shfl_xor(t1, 32);                                          \
    union { bf16x8 v; unsigned int u[4]; } pf;                                     \
    pf.u[0] = g ? r0  : w0;                                                        \
    pf.u[1] = g ? r1  : w1;                                                        \
    pf.u[2] = g ? wh0 : r0;                                                        \
    pf.u[3] = g ? wh1 : r1;                                                        \
    if (sl == 0) {                                                                 \
      AC0 = __builtin_amdgcn_mfma_f32_32x32x16_bf16(vC0, pf.v, AC0, 0, 0, 0);      \
      AC1 = __builtin_amdgcn_mfma_f32_32x32x16_bf16(vC2, pf.v, AC1, 0, 0, 0);      \
    } else {                                                                       \
      AC0 = __builtin_amdgcn_mfma_f32_32x32x16_bf16(vC1, pf.v, AC0, 0, 0, 0);      \
      AC1 = __builtin_amdgcn_mfma_f32_32x32x16_bf16(vC3, pf.v, AC1, 0, 0, 0);      \
    }                                                                              \
  }                                                                                \
} while (0)

__global__ __launch_bounds__(256, 3)
void attn_kernel(const unsigned short* __restrict__ qkv,
                 const unsigned short* __restrict__ Vf,
                 unsigned short* __restrict__ attnO) {
  __shared__ __align__(16) char smem[32768];   // 4 waves x K double-buffer 8KB
  const int tid = threadIdx.x;
  const int wid = tid >> 6, lane = tid & 63;
  const int g = lane >> 5, l31 = lane & 31;

  int bid = blockIdx.x;                   // 768 = 8 XCD chunks x 96
  int e = (bid & 7)*96 + (bid >> 3);
  int qt = e & 31;
  int hb = e >> 5;                        // 0..23
  int h = hb % 6, b = hb / 6;
  const int kvh = h / 3;
  const int tokA = b*SEQ + qt*64 + l31;
  const int tokB = tokA + 32;
  const int kvbase = wid * 512;

  char* kb0 = smem + wid*8192;

  bf16x8 qfA[4], qfB[4];
  #pragma unroll
  for (int s = 0; s < 4; ++s) {
    qfA[s] = *(const bf16x8*)(qkv + (size_t)tokA*NQKV + h*64 + s*16 + g*8);
    qfB[s] = *(const bf16x8*)(qkv + (size_t)tokB*NQKV + h*64 + s*16 + g*8);
  }

  f32x16 aA0, aA1, aB0, aB1;
  #pragma unroll
  for (int r = 0; r < 16; ++r) { aA0[r] = 0.f; aA1[r] = 0.f; aB0[r] = 0.f; aB1[r] = 0.f; }
  float mA = -1e30f, lA = 0.f, mB = -1e30f, lB = 0.f;

  const unsigned short* Kbase = qkv + (size_t)(b*SEQ)*NQKV + 384 + kvh*64;
  const unsigned short* Vfb = Vf + (size_t)(b*2 + kvh)*131072;

  stage_k(Kbase, kvbase, kb0, lane);      // K(0) -> buf 0

  bf16x8 vC0, vC1, vC2, vC3;
  for (int t = 0; t < 16; ++t) {
    const bool pref = (t < 15);
    // V fragment loads FIRST (must be older than K(t+1) stage)
    {
      const unsigned short* vp = Vfb + (size_t)(wid*16 + t)*2048 + lane*8;
      vC0 = *(const bf16x8*)(vp);
      vC1 = *(const bf16x8*)(vp + 512);
      vC2 = *(const bf16x8*)(vp + 1024);
      vC3 = *(const bf16x8*)(vp + 1536);
    }
    __builtin_amdgcn_sched_barrier(0);    // pin V-issue before K(t+1) stage
    if (pref) {
      stage_k(Kbase, kvbase + (t+1)*32, kb0 + ((t+1)&1)*4096, lane);
      WAITVN(8);                          // K(t) done; V(t)+K(t+1) in flight
    } else {
      WAITVN(4);                          // K(15) done; V(15) in flight
    }
    const char* kb = kb0 + (t&1)*4096;
    PROC_SUB(qfA, mA, lA, aA0, aA1);
    PROC_SUB(qfB, mB, lB, aB0, aB1);
  }

  // ---- 4-way flash combine through LDS (staging area is dead) ----
  lA += __shfl_xor(lA, 32);
  lB += __shfl_xor(lB, 32);
  __syncthreads();
  float* cmb  = (float*)(smem + 24576);   // [w][sub][m|l][32] = 2KB
  float* slab = (float*)smem;             // [3][64][32] fp32 = 24KB
  if (g == 0) {
    cmb[((wid*2+0)*2+0)*32 + l31] = mA;
    cmb[((wid*2+0)*2+1)*32 + l31] = lA;
    cmb[((wid*2+1)*2+0)*32 + l31] = mB;
    cmb[((wid*2+1)*2+1)*32 + l31] = lB;
  }
  __syncthreads();
  #pragma unroll
  for (int sub = 0; sub < 2; ++sub) {
    float m0 = cmb[((0*2+sub)*2+0)*32 + l31];
    float m1 = cmb[((1*2+sub)*2+0)*32 + l31];
    float m2 = cmb[((2*2+sub)*2+0)*32 + l31];
    float m3 = cmb[((3*2+sub)*2+0)*32 + l31];
    float M = fmaxf(fmaxf(m0, m1), fmaxf(m2, m3));
    float msub = sub ? mB : mA;
    float aw = exp2_fast(msub - M);
    f32x16 u0 = sub ? aB0 : aA0;
    f32x16 u1 = sub ? aB1 : aA1;
    if (wid != 0) {
      float* s = slab + (wid-1)*2048;
      #pragma unroll
      for (int dt = 0; dt < 2; ++dt)
        #pragma unroll
        for (int r = 0; r < 16; ++r) {
          int d = dt*32 + (r&3) + ((r>>2)<<3) + (g<<2);
          s[d*32 + l31] = (dt ? u1[r] : u0[r]) * aw;
        }
    }
    __syncthreads();
    if (wid == 0) {
      float l0 = cmb[((0*2+sub)*2+1)*32 + l31];
      float l1 = cmb[((1*2+sub)*2+1)*32 + l31];
      float l2 = cmb[((2*2+sub)*2+1)*32 + l31];
      float l3 = cmb[((3*2+sub)*2+1)*32 + l31];
      float lsum = l0*exp2_fast(m0-M) + l1*exp2_fast(m1-M)
                 + l2*exp2_fast(m2-M) + l3*exp2_fast(m3-M);
      float invl = 1.0f / lsum;
      int token = sub ? tokB : tokA;
      #pragma unroll
      for (int dt = 0; dt < 2; ++dt)
        #pragma unroll
        for (int q8 = 0; q8 < 4; ++q8) {
          union { unsigned short s[4]; uint2 u; } ov;
          #pragma unroll
          for (int j = 0; j < 4; ++j) {
            int r = q8*4 + j;
            int d = dt*32 + (r&3) + ((r>>2)<<3) + (g<<2);
            float tot = (dt ? u1[r] : u0[r]) * aw
                      + slab[0*2048 + d*32 + l31]
                      + slab[1*2048 + d*32 + l31]
                      + slab[2*2048 + d*32 + l31];
            ov.s[j] = f2bf(tot * invl);
          }
          int d0 = dt*32 + q8*8 + g*4;
          *(uint2*)(attnO + (size_t)token*DMODEL + h*64 + d0) = ov.u;
        }
    }
    __syncthreads();   // slabs reused by sub 1
  }
}

// ---------------------------------------------------------------------------
extern "C" void kernel_launch(void* const* d_in, const int* in_sizes, int n_in,
                              void* d_out, int out_size, void* d_ws, size_t ws_size,
                              hipStream_t stream) {
  const float* X    = (const float*)d_in[0];
  const float* Wq   = (const float*)d_in[1];
  const float* Wk   = (const float*)d_in[2];
  const float* Wv   = (const float*)d_in[3];
  const float* Wo   = (const float*)d_in[4];
  const float* fcos = (const float*)d_in[5];
  const float* fsin = (const float*)d_in[6];
  char* ws = (char*)d_ws;

  // ws layout (~19.7 MB; attnO overlays Xb, dead after the QKV GEMM)
  unsigned short* Xb    = (unsigned short*)(ws);                 // 6,291,456 B
  unsigned short* attnO = (unsigned short*)(ws);                 // overlay
  unsigned short* QKV   = (unsigned short*)(ws + 6291456);       // 10,485,760 B
  unsigned short* Vf    = (unsigned short*)(ws + 16777216);      //  2,097,152 B
  unsigned short* WT    = (unsigned short*)(ws + 18874368);      //    491,520 B
  unsigned short* WoT   = (unsigned short*)(ws + 19365888);      //    294,912 B

  prep_kernel<<<4608, 256, 0, stream>>>(X, Wq, Wk, Wv, Wo, Xb, WT, WoT);
  gemm_kernel<NQKV, true, true><<<dim3(64, 10), 256, 0, stream>>>(Xb, WT, QKV, fcos, fsin);
  vfrag_kernel<<<dim3(32, 2, 4), 256, 0, stream>>>(QKV, Vf);
  attn_kernel<<<768, 256, 0, stream>>>(QKV, Vf, attnO);
  gemm_kernel<DMODEL, false, false><<<dim3(64, 6), 256, 0, stream>>>(attnO, WoT, (void*)d_out, nullptr, nullptr);
}

// Round 9
// 149.594 us; speedup vs baseline: 1.1138x; 1.1138x over previous
//
#include <hip/hip_runtime.h>
#include <stdint.h>

// Problem constants
#define BATCH   4
#define SEQ     2048
#define DMODEL  384
#define NHEAD   6
#define NKVH    2
#define HD      64
#define MTOK    (BATCH*SEQ)   // 8192
#define NQKV    640           // 384 q + 128 k + 128 v
// 1/sqrt(HD) * log2(e): scores leave QK^T already in log2 domain -> raw v_exp_f32.
#define QSCALE  (0.125f * 1.4426950408889634f)

typedef __bf16 bf16x8 __attribute__((ext_vector_type(8)));
typedef float  f32x16 __attribute__((ext_vector_type(16)));
typedef unsigned int u32x2 __attribute__((ext_vector_type(2)));

__device__ inline unsigned short f2bf(float f) {
  union { float f; unsigned int u; } v; v.f = f;
  return (unsigned short)((v.u + 0x7fffu + ((v.u >> 16) & 1u)) >> 16); // RNE
}
__device__ inline float bf2f(unsigned short b) {
  union { unsigned int u; float f; } v; v.u = ((unsigned int)b) << 16;
  return v.f;
}
__device__ inline unsigned int cvtpk(float lo, float hi) {
  unsigned int r;
  asm("v_cvt_pk_bf16_f32 %0, %1, %2" : "=v"(r) : "v"(lo), "v"(hi));
  return r;
}
__device__ inline float exp2_fast(float x) {   // v_exp_f32: D = 2^S0
  float r;
  asm("v_exp_f32 %0, %1" : "=v"(r) : "v"(x));
  return r;
}

// Cross-half (lane^32) primitives. Builtin permlane32_swap (VALU) when
// available — returns {vdst', src0'} with vdst row1 <-> src0 row0 — else
// ds_bpermute-based __shfl_xor (R5-proven fallback).
#if __has_builtin(__builtin_amdgcn_permlane32_swap)
#define HAVE_PLSWAP 1
#else
#define HAVE_PLSWAP 0
#endif

__device__ inline float xhalf_max(float x) {
#if HAVE_PLSWAP
  union { float f; unsigned u; } c; c.f = x;
  u32x2 r = __builtin_amdgcn_permlane32_swap(c.u, c.u, false, false);
  union { unsigned u; float f; } a, b; a.u = r[0]; b.u = r[1];
  return fmaxf(a.f, b.f);
#else
  return fmaxf(x, __shfl_xor(x, 32));
#endif
}
__device__ inline float xhalf_sum(float x) {
#if HAVE_PLSWAP
  union { float f; unsigned u; } c; c.f = x;
  u32x2 r = __builtin_amdgcn_permlane32_swap(c.u, c.u, false, false);
  union { unsigned u; float f; } a, b; a.u = r[0]; b.u = r[1];
  return a.f + b.f;
#else
  return x + __shfl_xor(x, 32);
#endif
}
// P^T fragment exchange: a0=cvtpk(p0,p1), a1=cvtpk(p2,p3), b0=cvtpk(p4,p5),
// b1=cvtpk(p6,p7) -> u[0..3] = B-fragment words (HK T12 pattern).
__device__ inline void pv_exchange(unsigned a0, unsigned a1, unsigned b0, unsigned b1,
                                   unsigned (&u)[4], int g) {
#if HAVE_PLSWAP
  u32x2 e0 = __builtin_amdgcn_permlane32_swap(a0, b0, false, false);
  u32x2 e1 = __builtin_amdgcn_permlane32_swap(a1, b1, false, false);
  u[0] = e0[0]; u[1] = e1[0]; u[2] = e0[1]; u[3] = e1[1];
#else
  unsigned t0 = g ? a0 : b0, t1 = g ? a1 : b1;
  unsigned r0 = __shfl_xor(t0, 32), r1 = __shfl_xor(t1, 32);
  u[0] = g ? r0 : a0;
  u[1] = g ? r1 : a1;
  u[2] = g ? b0 : r0;
  u[3] = g ? b1 : r1;
#endif
}

#define GLOAD16(gsrc, ldst) __builtin_amdgcn_global_load_lds( \
    (const __attribute__((address_space(1))) void*)(gsrc), \
    (__attribute__((address_space(3))) void*)(ldst), 16, 0, 0)

// ---------------------------------------------------------------------------
// Kernel 1: prep — X fp32->bf16 ; WT[640][384] = [Wq|Wk|Wv]^T bf16 ; WoT bf16
// ---------------------------------------------------------------------------
__global__ void prep_kernel(const float* __restrict__ X,
                            const float* __restrict__ Wq, const float* __restrict__ Wk,
                            const float* __restrict__ Wv, const float* __restrict__ Wo,
                            unsigned short* __restrict__ Xb,
                            unsigned short* __restrict__ WT,
                            unsigned short* __restrict__ WoT) {
  int idx = blockIdx.x * 256 + threadIdx.x;
  if (idx < (MTOK*DMODEL)/4) {
    float4 v = ((const float4*)X)[idx];
    union { unsigned short s[4]; uint2 u; } o;
    o.s[0] = f2bf(v.x); o.s[1] = f2bf(v.y); o.s[2] = f2bf(v.z); o.s[3] = f2bf(v.w);
    ((uint2*)Xb)[idx] = o.u;
  } else if (idx < (MTOK*DMODEL)/4 + NQKV*DMODEL) {
    int j = idx - (MTOK*DMODEL)/4;
    int n = j / DMODEL, k = j % DMODEL;
    float val = (n < 384) ? Wq[k*384 + n]
              : (n < 512) ? Wk[k*128 + (n-384)]
                          : Wv[k*128 + (n-512)];
    WT[j] = f2bf(val);
  } else if (idx < (MTOK*DMODEL)/4 + NQKV*DMODEL + DMODEL*DMODEL) {
    int j = idx - (MTOK*DMODEL)/4 - NQKV*DMODEL;
    int n = j / DMODEL, k = j % DMODEL;
    WoT[j] = f2bf(Wo[k*384 + n]);
  }
}

// ---------------------------------------------------------------------------
// Kernel 2/5: bf16 MFMA GEMM  C[M][NCOLS] = A[M][384] * BT[NCOLS][384]^T
// tile 128x64, BK=64, 4 waves (2x2), 32x32x16 MFMA. RoPE fused in epilogue.
// ---------------------------------------------------------------------------
template<int NCOLS, bool OUT_BF16, bool ROPE>
__global__ __launch_bounds__(256, 2)
void gemm_kernel(const unsigned short* __restrict__ A,
                 const unsigned short* __restrict__ BT,
                 void* __restrict__ Cout,
                 const float* __restrict__ fcos,
                 const float* __restrict__ fsin) {
  __shared__ unsigned short ldsA[128*64];
  __shared__ unsigned short ldsB[64*64];
  const int tid = threadIdx.x;
  const int wid = tid >> 6, lane = tid & 63;
  const int g = lane >> 5, l31 = lane & 31;
  const int wm = wid >> 1, wn = wid & 1;
  const int mbase = blockIdx.x * 128, nbase = blockIdx.y * 64;

  f32x16 c[2];
  #pragma unroll
  for (int i = 0; i < 2; ++i)
    #pragma unroll
    for (int r = 0; r < 16; ++r) c[i][r] = 0.f;

  for (int kt = 0; kt < DMODEL; kt += 64) {
    #pragma unroll
    for (int i = 0; i < 4; ++i) {
      int L = ((wid*4 + i) << 10) + lane*16;
      int row = L >> 7;
      int slot = (lane & 7) ^ (row & 7);
      GLOAD16(A + (mbase + row)*DMODEL + kt + slot*8, ((char*)ldsA) + L);
    }
    #pragma unroll
    for (int i = 0; i < 2; ++i) {
      int L = ((wid*2 + i) << 10) + lane*16;
      int row = L >> 7;
      int slot = (lane & 7) ^ (row & 7);
      GLOAD16(BT + (nbase + row)*DMODEL + kt + slot*8, ((char*)ldsB) + L);
    }
    __syncthreads();

    bf16x8 bf[4];
    {
      int row = wn*32 + l31;
      #pragma unroll
      for (int s = 0; s < 4; ++s) {
        int slot = ((s<<1) | g) ^ (row & 7);
        bf[s] = *(const bf16x8*)(((const char*)ldsB) + row*128 + slot*16);
      }
    }
    #pragma unroll
    for (int mt = 0; mt < 2; ++mt) {
      int row = wm*64 + mt*32 + l31;
      #pragma unroll
      for (int s = 0; s < 4; ++s) {
        int slot = ((s<<1) | g) ^ (row & 7);
        bf16x8 af = *(const bf16x8*)(((const char*)ldsA) + row*128 + slot*16);
        c[mt] = __builtin_amdgcn_mfma_f32_32x32x16_bf16(af, bf[s], c[mt], 0, 0, 0);
      }
    }
    __syncthreads();
  }

  const int n = nbase + wn*32 + l31;
  const bool isqk = ROPE && (nbase < 512);
  const float rscale = (nbase < 384) ? QSCALE : 1.0f;
  const int ri = (n & 63) >> 1;
  const bool odd = (n & 1) != 0;

  #pragma unroll
  for (int mt = 0; mt < 2; ++mt)
    #pragma unroll
    for (int rr = 0; rr < 16; ++rr) {
      int m = mbase + wm*64 + mt*32 + (rr&3) + ((rr>>2)<<3) + (g<<2);
      float val = c[mt][rr];
      if (isqk) {
        float xp = __shfl_xor(val, 1);
        int s = m & (SEQ-1);
        float cs = fcos[s*32 + ri], sn = fsin[s*32 + ri];
        val = odd ? (xp*sn + val*cs) : (val*cs - xp*sn);
        val *= rscale;
      }
      if (OUT_BF16) ((unsigned short*)Cout)[m*NCOLS + n] = f2bf(val);
      else          ((float*)Cout)[m*NCOLS + n] = val;
    }
}

// ---------------------------------------------------------------------------
// Kernel 3: V -> MFMA-fragment layout
// Vf[(b*2+kvh)][tile(64)][dt(2)][sl(2)][lane(64)][8 bf16]
// content: V[s = tile*32 + sl*16 + (lane>>5)*8 + j][hd = dt*32 + (lane&31)]
// ---------------------------------------------------------------------------
__global__ void vfrag_kernel(const unsigned short* __restrict__ qkv,
                             unsigned short* __restrict__ Vf) {
  __shared__ unsigned short tile[64][72];
  int t = threadIdx.x;
  int s0 = blockIdx.x * 64;
  int kvh = blockIdx.y;
  int b = blockIdx.z;
  #pragma unroll
  for (int p = 0; p < 2; ++p) {
    int row = (t >> 3) + p*32;
    int c8 = t & 7;
    uint4 v = *(const uint4*)(qkv + (size_t)(b*SEQ + s0 + row)*NQKV + 512 + kvh*64 + c8*8);
    *(uint4*)(&tile[row][c8*8]) = v;
  }
  __syncthreads();
  unsigned short* base = Vf + (size_t)(b*2 + kvh)*131072;
  #pragma unroll
  for (int p = 0; p < 2; ++p) {
    int c = t + p*256;           // 0..511
    int tloc = c >> 8;
    int r = c & 255;
    int dt = r >> 7, sl = (r >> 6) & 1, lane = r & 63;
    int gg = lane >> 5, ll = lane & 31;
    union { unsigned short s[8]; uint4 v; } o;
    #pragma unroll
    for (int j = 0; j < 8; ++j)
      o.s[j] = tile[tloc*32 + sl*16 + gg*8 + j][dt*32 + ll];
    *(uint4*)(base + (size_t)(s0/32 + tloc)*2048 + (dt*2 + sl)*512 + lane*8) = o.v;
  }
}

// ---------------------------------------------------------------------------
// Kernel 4: flash attention — 1 wave/block, barrier-free, kv-split 2.
// grid (1536, 2). K double-buffered in LDS (8KB); V fragments direct
// global->VGPR (prefetch depth 1). Counted vmcnt(8): at the wait point the
// outstanding set is {K(t+1):4, V(t+1):4}; K(t)+V(t) are complete.
// Cross-half exchanges via __builtin_amdgcn_permlane32_swap (VALU) — no LDS
// round trip on the softmax->PV critical chain. Partials to ws; combine
// kernel merges the two kv halves.
// ---------------------------------------------------------------------------
__device__ __forceinline__ void stage_k(const unsigned short* Kbase, int kv0,
                                        char* kbuf, int lane) {
  #pragma unroll
  for (int i = 0; i < 4; ++i) {
    int L = (i << 10) + lane*16;
    int row = L >> 7;
    int slot = (lane & 7) ^ (row & 7);
    GLOAD16(Kbase + (size_t)(kv0 + row)*NQKV + slot*8, kbuf + L);
  }
}

#define ATTN_BODY(T, VC0, VC1, VC2, VC3, VN0, VN1, VN2, VN3, PREF) do {            \
  if (PREF) {                                                                      \
    stage_k(Kbase, kvbase + ((T)+1)*32, kbuf + (((T)+1)&1)*4096, lane);            \
    const unsigned short* vp = Vfb + (size_t)(part*32 + (T)+1)*2048;               \
    VN0 = *(const bf16x8*)(vp + lane*8);                                           \
    VN1 = *(const bf16x8*)(vp + 512 + lane*8);                                     \
    VN2 = *(const bf16x8*)(vp + 1024 + lane*8);                                    \
    VN3 = *(const bf16x8*)(vp + 1536 + lane*8);                                    \
    asm volatile("s_waitcnt vmcnt(8)" ::: "memory");                               \
  } else {                                                                         \
    asm volatile("s_waitcnt vmcnt(0)" ::: "memory");                               \
  }                                                                                \
  const char* kb = kbuf + ((T)&1)*4096;                                            \
  f32x16 c1;                                                                       \
  _Pragma("unroll")                                                                \
  for (int r = 0; r < 16; ++r) c1[r] = 0.f;                                        \
  _Pragma("unroll")                                                                \
  for (int s = 0; s < 4; ++s) {                                                    \
    int slot = ((s<<1) | g) ^ (l31 & 7);                                           \
    bf16x8 kf = *(const bf16x8*)(kb + l31*128 + slot*16);                          \
    c1 = __builtin_amdgcn_mfma_f32_32x32x16_bf16(kf, qf[s], c1, 0, 0, 0);          \
  }                                                                                \
  float x0 = fmaxf(c1[0],c1[1]), x1 = fmaxf(c1[2],c1[3]);                          \
  float x2 = fmaxf(c1[4],c1[5]), x3 = fmaxf(c1[6],c1[7]);                          \
  float x4 = fmaxf(c1[8],c1[9]), x5 = fmaxf(c1[10],c1[11]);                        \
  float x6 = fmaxf(c1[12],c1[13]), x7 = fmaxf(c1[14],c1[15]);                      \
  float y0 = fmaxf(x0,x1), y1 = fmaxf(x2,x3), y2 = fmaxf(x4,x5), y3 = fmaxf(x6,x7);\
  float pmax = fmaxf(fmaxf(y0,y1), fmaxf(y2,y3));                                  \
  pmax = xhalf_max(pmax);                                                          \
  if (!__all(pmax <= mrun + 10.f)) {                                               \
    float mnew = fmaxf(mrun, pmax);                                                \
    float alpha = exp2_fast(mrun - mnew);                                          \
    _Pragma("unroll")                                                              \
    for (int r = 0; r < 16; ++r) { acc0[r] *= alpha; acc1[r] *= alpha; }           \
    lrun *= alpha;                                                                 \
    mrun = mnew;                                                                   \
  }                                                                                \
  float p[16];                                                                     \
  _Pragma("unroll")                                                                \
  for (int r = 0; r < 16; ++r) p[r] = exp2_fast(c1[r] - mrun);                     \
  {                                                                                \
    float s0_ = (p[0]+p[1])+(p[2]+p[3]), s1_ = (p[4]+p[5])+(p[6]+p[7]);            \
    float s2_ = (p[8]+p[9])+(p[10]+p[11]), s3_ = (p[12]+p[13])+(p[14]+p[15]);      \
    lrun += (s0_+s1_)+(s2_+s3_);                                                   \
  }                                                                                \
  _Pragma("unroll")                                                                \
  for (int sl = 0; sl < 2; ++sl) {                                                 \
    int rb = sl*8;                                                                 \
    unsigned int a0_ = cvtpk(p[rb+0], p[rb+1]);                                    \
    unsigned int a1_ = cvtpk(p[rb+2], p[rb+3]);                                    \
    unsigned int b0_ = cvtpk(p[rb+4], p[rb+5]);                                    \
    unsigned int b1_ = cvtpk(p[rb+6], p[rb+7]);                                    \
    union { bf16x8 v; unsigned int u[4]; } pf;                                     \
    pv_exchange(a0_, a1_, b0_, b1_, pf.u, g);                                      \
    if (sl == 0) {                                                                 \
      acc0 = __builtin_amdgcn_mfma_f32_32x32x16_bf16(VC0, pf.v, acc0, 0, 0, 0);    \
      acc1 = __builtin_amdgcn_mfma_f32_32x32x16_bf16(VC2, pf.v, acc1, 0, 0, 0);    \
    } else {                                                                       \
      acc0 = __builtin_amdgcn_mfma_f32_32x32x16_bf16(VC1, pf.v, acc0, 0, 0, 0);    \
      acc1 = __builtin_amdgcn_mfma_f32_32x32x16_bf16(VC3, pf.v, acc1, 0, 0, 0);    \
    }                                                                              \
  }                                                                                \
} while (0)

__global__ __launch_bounds__(64, 3)
void attn_kernel(const unsigned short* __restrict__ qkv,
                 const unsigned short* __restrict__ Vf,
                 unsigned short* __restrict__ PO0,
                 unsigned short* __restrict__ PO1,
                 float2* __restrict__ ML) {
  __shared__ __align__(16) char kbuf[8192];
  const int lane = threadIdx.x;
  const int g = lane >> 5, l31 = lane & 31;

  int bid = blockIdx.x;
  const int part = blockIdx.y;
  int e = (bid & 7)*192 + (bid >> 3);     // bijective XCD swizzle (1536 = 8*192)
  int qt = e & 63;
  int hb = e >> 6;
  int h = hb % 6, b = hb / 6;
  const int kvh = h / 3;
  const int token = b*SEQ + qt*32 + l31;
  const int kvbase = part * (SEQ/2);

  bf16x8 qf[4];
  #pragma unroll
  for (int s = 0; s < 4; ++s)
    qf[s] = *(const bf16x8*)(qkv + (size_t)token*NQKV + h*64 + s*16 + g*8);

  f32x16 acc0, acc1;
  #pragma unroll
  for (int r = 0; r < 16; ++r) { acc0[r] = 0.f; acc1[r] = 0.f; }
  float mrun = -1e30f, lrun = 0.f;

  const unsigned short* Kbase = qkv + (size_t)(b*SEQ)*NQKV + 384 + kvh*64;
  const unsigned short* Vfb = Vf + (size_t)(b*2 + kvh)*131072;

  bf16x8 vA0, vA1, vA2, vA3, vB0, vB1, vB2, vB3;

  // prologue: batch 0 (K tile 0 -> buf0, V frags tile 0 -> set A)
  stage_k(Kbase, kvbase, kbuf, lane);
  {
    const unsigned short* vp = Vfb + (size_t)(part*32)*2048;
    vA0 = *(const bf16x8*)(vp + lane*8);
    vA1 = *(const bf16x8*)(vp + 512 + lane*8);
    vA2 = *(const bf16x8*)(vp + 1024 + lane*8);
    vA3 = *(const bf16x8*)(vp + 1536 + lane*8);
  }

  for (int tt = 0; tt < 30; tt += 2) {
    ATTN_BODY(tt,   vA0, vA1, vA2, vA3, vB0, vB1, vB2, vB3, true);
    ATTN_BODY(tt+1, vB0, vB1, vB2, vB3, vA0, vA1, vA2, vA3, true);
  }
  ATTN_BODY(30, vA0, vA1, vA2, vA3, vB0, vB1, vB2, vB3, true);
  ATTN_BODY(31, vB0, vB1, vB2, vB3, vA0, vA1, vA2, vA3, false);

  // epilogue: merge g-halves of l; write unnorm O (bf16) + (m,l)
  lrun = xhalf_sum(lrun);
  unsigned short* PO = part ? PO1 : PO0;
  #pragma unroll
  for (int dt = 0; dt < 2; ++dt)
    #pragma unroll
    for (int q8 = 0; q8 < 4; ++q8) {
      union { unsigned short s[4]; uint2 u; } ov;
      #pragma unroll
      for (int j = 0; j < 4; ++j) {
        int r = q8*4 + j;
        ov.s[j] = f2bf(dt ? acc1[r] : acc0[r]);
      }
      int d = dt*32 + q8*8 + g*4;
      *(uint2*)(PO + (size_t)token*DMODEL + h*64 + d) = ov.u;
    }
  if (g == 0)
    ML[(size_t)part*49152 + token*6 + h] = make_float2(mrun, lrun);
}

// ---------------------------------------------------------------------------
// Kernel 5b: combine the two kv-split partials -> attnO bf16
// ---------------------------------------------------------------------------
__global__ void combine_kernel(const unsigned short* __restrict__ PO0,
                               const unsigned short* __restrict__ PO1,
                               const float2* __restrict__ ML,
                               unsigned short* __restrict__ attnO) {
  int idx = blockIdx.x*256 + threadIdx.x;   // 393216 chunks of 8 elems
  int token = idx / 48;
  int c8 = idx - token*48;
  int h = c8 >> 3;
  float2 ml0 = ML[token*6 + h];
  float2 ml1 = ML[49152 + token*6 + h];
  float M = fmaxf(ml0.x, ml1.x);
  float a0 = exp2_fast(ml0.x - M), a1 = exp2_fast(ml1.x - M);
  float inv = 1.0f / (ml0.y*a0 + ml1.y*a1);
  float s0 = a0*inv, s1 = a1*inv;
  union { unsigned short s[8]; uint4 v; } p0, p1, o;
  p0.v = *(const uint4*)(PO0 + (size_t)idx*8);
  p1.v = *(const uint4*)(PO1 + (size_t)idx*8);
  #pragma unroll
  for (int j = 0; j < 8; ++j)
    o.s[j] = f2bf(bf2f(p0.s[j])*s0 + bf2f(p1.s[j])*s1);
  *(uint4*)(attnO + (size_t)idx*8) = o.v;
}

// ---------------------------------------------------------------------------
extern "C" void kernel_launch(void* const* d_in, const int* in_sizes, int n_in,
                              void* d_out, int out_size, void* d_ws, size_t ws_size,
                              hipStream_t stream) {
  const float* X    = (const float*)d_in[0];
  const float* Wq   = (const float*)d_in[1];
  const float* Wk   = (const float*)d_in[2];
  const float* Wv   = (const float*)d_in[3];
  const float* Wo   = (const float*)d_in[4];
  const float* fcos = (const float*)d_in[5];
  const float* fsin = (const float*)d_in[6];
  char* ws = (char*)d_ws;

  // ws layout (PO0 overlays Xb, which is dead after the QKV GEMM):
  unsigned short* Xb    = (unsigned short*)(ws);                 // 6,291,456 B
  unsigned short* PO0   = (unsigned short*)(ws);                 // reuse
  unsigned short* QKV   = (unsigned short*)(ws + 6291456);       // 10,485,760 B
  unsigned short* Vf    = (unsigned short*)(ws + 16777216);      //  2,097,152 B
  unsigned short* attnO = (unsigned short*)(ws + 18874368);      //  6,291,456 B
  unsigned short* WT    = (unsigned short*)(ws + 25165824);      //    491,520 B
  unsigned short* WoT   = (unsigned short*)(ws + 25657344);      //    294,912 B
  unsigned short* PO1   = (unsigned short*)(ws + 25952256);      //  6,291,456 B
  float2*         ML    = (float2*)       (ws + 32243712);       //    786,432 B

  prep_kernel<<<4608, 256, 0, stream>>>(X, Wq, Wk, Wv, Wo, Xb, WT, WoT);
  gemm_kernel<NQKV, true, true><<<dim3(64, 10), 256, 0, stream>>>(Xb, WT, QKV, fcos, fsin);
  vfrag_kernel<<<dim3(32, 2, 4), 256, 0, stream>>>(QKV, Vf);
  attn_kernel<<<dim3(1536, 2), 64, 0, stream>>>(QKV, Vf, PO0, PO1, ML);
  combine_kernel<<<1536, 256, 0, stream>>>(PO0, PO1, ML, attnO);
  gemm_kernel<DMODEL, false, false><<<dim3(64, 6), 256, 0, stream>>>(attnO, WoT, (void*)d_out, nullptr, nullptr);
}